// Round 14
// baseline (372.488 us; speedup 1.0000x reference)
//
#include <hip/hip_runtime.h>

#define N_SEQ 2048
#define M_FFT 4096
#define D1    1536
#define NH    8
#define HD    192
#define ED    512

typedef __bf16 bf16;
typedef __bf16 bf16x4 __attribute__((ext_vector_type(4)));
typedef __bf16 bf16x8 __attribute__((ext_vector_type(8)));
typedef float  floatx4 __attribute__((ext_vector_type(4)));
typedef float  cx __attribute__((ext_vector_type(2)));   // complex as packed fp32

enum { MODE_PLAIN = 0, MODE_SILU_UV = 1, MODE_AT = 3, MODE_RPE = 4 };

__device__ __forceinline__ void gload16(const void* g, void* l) {
    __builtin_amdgcn_global_load_lds(
        (const __attribute__((address_space(1))) void*)g,
        (__attribute__((address_space(3))) void*)l, 16, 0, 0);
}

// same-wave LDS hand-off: commit prior ds_writes + compiler fence.
// Valid only when producer and consumer threads are in the same wave
// (DS ops of a wave execute in order).
#define WAVE_LDS_FENCE() asm volatile("s_waitcnt lgkmcnt(0)" ::: "memory")

// ---------------------------------------------------------------------------
// bf16 MFMA GEMM, depth-3 pipeline with COUNTED vmcnt (T4), BN-templated,
// + T2 granule-XOR LDS swizzle + T5 setprio.
// SILU_UV / AT epilogues transpose through LDS (reusing dead staging bufs).
// ---------------------------------------------------------------------------
template<int MODE, int BN, typename OutT>
__global__ __launch_bounds__(256) void gemm_bf16(
    const bf16* __restrict__ A, const bf16* __restrict__ Bw,
    const float* __restrict__ bias, const float* __restrict__ bias2,
    OutT* __restrict__ C, OutT* __restrict__ C2,
    int M, int Nc, int K,
    const float* __restrict__ scale_in, float* __restrict__ sumsq_out)
{
    constexpr int NJ  = BN / 32;           // n-fragments per wave (4 or 2)
    constexpr int ASZ = 3 * 128 * 32;
    constexpr int BSZ = 3 * BN * 32;
    __shared__ __align__(16) bf16 smem[ASZ + BSZ];
    bf16* As = smem;
    bf16* Bs = smem + ASZ;

    const int tid  = threadIdx.x;
    const int row0 = blockIdx.y * 128;
    const int col0 = blockIdx.x * BN;
    const int wid  = tid >> 6;
    const int lane = tid & 63;
    const int lm   = lane & 15;
    const int lk   = lane >> 4;
    const int wm   = wid >> 1;
    const int wn   = wid & 1;
    const int ldrow  = tid >> 2;
    // T2 write-side: source granule = (tid&3) ^ ((row>>1)&3), row = tid>>2
    const int ldcol8 = (((tid & 3) ^ ((tid >> 3) & 3))) * 8;
    // T2 read-side: granule = lk ^ ((row>>1)&3) = lk ^ ((lm>>1)&3)
    const int gsw = (lk ^ ((lm >> 1) & 3)) * 8;

    floatx4 acc[4][NJ] = {};

    const bf16* Ag = A  + ((size_t)(row0 + ldrow)) * K + ldcol8;
    const bf16* Bg = Bw + ((size_t)(col0 + ldrow)) * K + ldcol8;
    const int woff = (wid * 16) * 32;

    auto stage = [&](int t, int buf) {
        const int k0 = t << 5;
        gload16(Ag + k0, &As[buf * (128 * 32) + woff]);
        gload16(Ag + (size_t)64 * K + k0, &As[buf * (128 * 32) + woff + 64 * 32]);
        gload16(Bg + k0, &Bs[buf * (BN * 32) + woff]);
        if constexpr (BN == 128)
            gload16(Bg + (size_t)64 * K + k0, &Bs[buf * (BN * 32) + woff + 64 * 32]);
    };
    auto compute = [&](int buf) {
        bf16x8 af[4], bfr[NJ];
        #pragma unroll
        for (int mi = 0; mi < 4; ++mi)
            af[mi] = *(const bf16x8*)&As[buf * (128 * 32) + (wm * 64 + mi * 16 + lm) * 32 + gsw];
        #pragma unroll
        for (int nj = 0; nj < NJ; ++nj)
            bfr[nj] = *(const bf16x8*)&Bs[buf * (BN * 32) + (wn * (BN / 2) + nj * 16 + lm) * 32 + gsw];
        __builtin_amdgcn_s_setprio(1);                 // T5
        #pragma unroll
        for (int mi = 0; mi < 4; ++mi)
            #pragma unroll
            for (int nj = 0; nj < NJ; ++nj)
                acc[mi][nj] = __builtin_amdgcn_mfma_f32_16x16x32_bf16(
                    af[mi], bfr[nj], acc[mi][nj], 0, 0, 0);
        __builtin_amdgcn_s_setprio(0);
    };

    const int nt = K >> 5;           // 16 or 48
    stage(0, 0);
    stage(1, 1);
    int sb = 2, cb = 0;
    for (int t = 0; t < nt; ++t) {
        __builtin_amdgcn_s_barrier();          // A: compute(t-1) done everywhere
        __builtin_amdgcn_sched_barrier(0);
        if (t + 2 < nt) {
            stage(t + 2, sb);
            if (++sb == 3) sb = 0;
        }
        // own tile-t loads complete; next two tiles stay in flight
        if (t < nt - 2) {
            if constexpr (BN == 128) asm volatile("s_waitcnt vmcnt(8)" ::: "memory");
            else                     asm volatile("s_waitcnt vmcnt(6)" ::: "memory");
        } else if (t == nt - 2) {
            if constexpr (BN == 128) asm volatile("s_waitcnt vmcnt(4)" ::: "memory");
            else                     asm volatile("s_waitcnt vmcnt(3)" ::: "memory");
        } else {
            asm volatile("s_waitcnt vmcnt(0)" ::: "memory");
        }
        __builtin_amdgcn_s_barrier();          // B: tile t fully in LDS (all waves)
        __builtin_amdgcn_sched_barrier(0);
        compute(cb);
        if (++cb == 3) cb = 0;
    }

    const float* bs = bias;
    OutT* dst = C;
    int cadj = 0;
    if (MODE == MODE_SILU_UV && col0 >= D1) { bs = bias2; dst = C2; cadj = D1; }

    float bcol[NJ];
    #pragma unroll
    for (int nj = 0; nj < NJ; ++nj)
        bcol[nj] = bs[col0 - cadj + wn * (BN / 2) + nj * 16 + lm];

    if (MODE == MODE_RPE) {
        #pragma unroll
        for (int mi = 0; mi < 4; ++mi) {
            #pragma unroll
            for (int r = 0; r < 4; ++r) {
                const int row = row0 + wm * 64 + mi * 16 + lk * 4 + r;
                float sc = 1.0f;
                if (scale_in)
                    sc = 1.0f / (sqrtf(scale_in[row]) * 0.04419417382415922f + 1e-8f);
                float ssq = 0.0f;
                #pragma unroll
                for (int nj = 0; nj < NJ; ++nj) {
                    const int col = col0 + wn * (BN / 2) + nj * 16 + lm;
                    float val = acc[mi][nj][r] * sc + bcol[nj];
                    ssq += val * val;
                    ((bf16*)C)[(size_t)row * Nc + col] = (bf16)fmaxf(val, 0.0f);
                }
                ssq += __shfl_xor(ssq, 1, 64);
                ssq += __shfl_xor(ssq, 2, 64);
                ssq += __shfl_xor(ssq, 4, 64);
                ssq += __shfl_xor(ssq, 8, 64);
                if (lm == 0) atomicAdd(&sumsq_out[row], ssq);
            }
        }
        return;
    }

    if (MODE == MODE_SILU_UV) {
        // ---- transpose-through-LDS coalesced store (128 x 128 tile) ----
        constexpr int TP = 136;                 // row pad: 16B-aligned rows
        bf16* T = smem;                         // 128*136*2 = 34816 B <= 48K
        __syncthreads();                        // K-loop LDS reads done
        #pragma unroll
        for (int mi = 0; mi < 4; ++mi) {
            const int rl = wm * 64 + mi * 16 + lk * 4;
            #pragma unroll
            for (int nj = 0; nj < NJ; ++nj) {
                const int cl = wn * 64 + nj * 16 + lm;
                bf16x4 o;
                #pragma unroll
                for (int r = 0; r < 4; ++r) {
                    float val = acc[mi][nj][r] + bcol[nj];
                    val = val * __fdividef(1.0f, 1.0f + __expf(-val));
                    o[r] = (bf16)val;
                }
                *(bf16x4*)&T[cl * TP + rl] = o;
            }
        }
        __syncthreads();
        const int b  = row0 >> 11;
        const int s0 = row0 & 2047;
        #pragma unroll
        for (int j = 0; j < 8; ++j) {
            const int idx = j * 256 + tid;      // [0, 2048)
            const int sc  = (idx & 15) * 8;     // s-chunk (16 consecutive tids)
            const int c   = idx >> 4;           // column 0..127
            bf16x8 o = *(const bf16x8*)&T[c * TP + sc];
            *(bf16x8*)&((bf16*)dst)[((size_t)(b * D1 + col0 - cadj + c)) * N_SEQ + s0 + sc] = o;
        }
        return;
    }

    if (MODE == MODE_AT) {
        // ---- transpose-through-LDS coalesced fp32 store (64 x 128 tile) ----
        constexpr int TP = 132;                 // fp32 row pad (16B-aligned)
        float* Tf = (float*)smem;               // 64*132*4 = 33792 B <= 36864
        __syncthreads();
        #pragma unroll
        for (int mi = 0; mi < 4; ++mi) {
            const int rbase = row0 + wm * 64 + mi * 16 + lk * 4;
            const int rl    = wm * 64 + mi * 16 + lk * 4;
            float sc[4];
            #pragma unroll
            for (int r = 0; r < 4; ++r)
                sc[r] = scale_in
                    ? 1.0f / (sqrtf(scale_in[rbase + r]) * 0.04419417382415922f + 1e-8f)
                    : 1.0f;
            #pragma unroll
            for (int nj = 0; nj < NJ; ++nj) {
                const int cl = wn * (BN / 2) + nj * 16 + lm;
                float4 o;
                o.x = acc[mi][nj][0] * sc[0] + bcol[nj];
                o.y = acc[mi][nj][1] * sc[1] + bcol[nj];
                o.z = acc[mi][nj][2] * sc[2] + bcol[nj];
                o.w = acc[mi][nj][3] * sc[3] + bcol[nj];
                *(float4*)&Tf[cl * TP + rl] = o;
            }
        }
        __syncthreads();
        #pragma unroll
        for (int j = 0; j < 8; ++j) {
            const int idx = j * 256 + tid;      // [0, 2048)
            const int rc  = (idx & 31) * 4;     // row-chunk (32 consecutive tids)
            const int c   = idx >> 5;           // column 0..63
            float4 o = *(const float4*)&Tf[c * TP + rc];
            *(float4*)&((float*)C)[(size_t)(col0 + c) * M + row0 + rc] = o;
        }
        return;
    }

    // MODE_PLAIN: row-major contiguous store (already coalesced enough)
    #pragma unroll
    for (int mi = 0; mi < 4; ++mi) {
        const int rbase = row0 + wm * 64 + mi * 16 + lk * 4;
        #pragma unroll
        for (int nj = 0; nj < NJ; ++nj) {
            const int col = col0 + wn * (BN / 2) + nj * 16 + lm;
            #pragma unroll
            for (int r = 0; r < 4; ++r) {
                float val = acc[mi][nj][r] + bcol[nj];
                C[(size_t)(rbase + r) * Nc + col] = (OutT)val;
            }
        }
    }
}

// ---------------------------------------------------------------------------
// mega-prologue: x convert + 5 weight converts + sumsq zero +
// RPE input layer w/ srms + FFT twiddle table (256 x 16 cx)
// ---------------------------------------------------------------------------
__global__ __launch_bounds__(256) void f2b_all_kernel(
    const float* __restrict__ x,  const float* __restrict__ s0,
    const float* __restrict__ s1, const float* __restrict__ s2,
    const float* __restrict__ s3, const float* __restrict__ s4,
    const float* __restrict__ Wp, const float* __restrict__ bp,
    bf16* __restrict__ x_bf, bf16* __restrict__ w_bf,
    float* __restrict__ sumsq, bf16* __restrict__ g0,
    float* __restrict__ twd)
{
    const int bid = blockIdx.x;
    const int tid = threadIdx.x;
    __shared__ float red[4];

    if (bid < 7936) {
        const float* src;
        bf16* dst;
        size_t off;
        if (bid < 4096) {
            src = x; dst = x_bf; off = (size_t)bid * 1024;
        } else {
            int t = bid - 4096;
            int seg = t / 768;
            src = seg == 0 ? s0 : seg == 1 ? s1 : seg == 2 ? s2
                : seg == 3 ? s3 : s4;
            dst = w_bf + (size_t)seg * 786432;
            off = (size_t)(t % 768) * 1024;
        }
        size_t i = off + (size_t)tid * 4;
        float4 f = *(const float4*)(src + i);
        union { bf16 h[4]; short4 s; } u4;
        u4.h[0] = (bf16)f.x; u4.h[1] = (bf16)f.y;
        u4.h[2] = (bf16)f.z; u4.h[3] = (bf16)f.w;
        *(short4*)(dst + i) = u4.s;
    } else if (bid < 7948) {
        size_t i = (size_t)(bid - 7936) * 1024 + (size_t)tid * 4;
        *(float4*)(sumsq + i) = make_float4(0.f, 0.f, 0.f, 0.f);
    } else if (bid < 12044) {
        const int j = bid - 7948;
        float idxv = (j < N_SEQ) ? (float)j
                                 : (j == N_SEQ ? 0.0f : (float)(j - 2 * N_SEQ));
        float h1 = idxv * Wp[tid] + bp[tid];
        float h2 = idxv * Wp[tid + 256] + bp[tid + 256];
        float ss = h1 * h1 + h2 * h2;
        #pragma unroll
        for (int off = 32; off > 0; off >>= 1) ss += __shfl_down(ss, off, 64);
        if ((tid & 63) == 0) red[tid >> 6] = ss;
        __syncthreads();
        float tot = red[0] + red[1] + red[2] + red[3];
        float scale = 1.0f / (sqrtf(tot) * 0.04419417382415922f + 1e-8f);
        g0[(size_t)j * ED + tid]       = (bf16)fmaxf(h1 * scale, 0.0f);
        g0[(size_t)j * ED + tid + 256] = (bf16)fmaxf(h2 * scale, 0.0f);
    } else {
        const int idx = (bid - 12044) * 256 + tid;    // [0, 4096)
        const int j = idx >> 4, tau = idx & 15;
        float sA, cA;
        __sincosf(-6.283185307179586f * (float)(j * tau) * (1.0f / 4096.0f),
                  &sA, &cA);
        cx w; w.x = cA; w.y = sA;
        ((cx*)twd)[idx] = w;
    }
}

// ---------------------------------------------------------------------------
// Radix-16 FFT, radix-4 butterflies, packed-fp32 complex.
// LDS addressing: fpad(base + s*t) = fpad(base) + s'*t  (256->274, 16->17, 1->1)
// Stage-1/inv-3 twiddle row in REGISTERS (inverse = conjugate);
// stage-2/inv-2 rows (16 distinct) in a 2 KB LDS broadcast table.
// SYNC: s2->s3 and inv1->inv2 are same-wave hand-offs (WAVE_LDS_FENCE).
// ---------------------------------------------------------------------------
#define FFT_LDS_SZ 4381

__device__ __forceinline__ int fpad(int i) { return i + (i >> 4) + 2 * (i >> 8); }

__device__ __forceinline__ cx mkcx(float a, float b) { cx r; r.x = a; r.y = b; return r; }
__device__ __forceinline__ cx cmul(cx a, cx b) {
    cx br = mkcx(-b.y, b.x);
    return a.xx * b + a.yy * br;
}
__device__ __forceinline__ cx cmul_cj(cx a, cx b) {      // a * conj(b)
    cx bc = mkcx(b.x, -b.y);
    cx br = mkcx(b.y, b.x);
    return a.xx * bc + a.yy * br;
}
__device__ __forceinline__ cx cneg_i(cx a) { return mkcx(a.y, -a.x); }   // a * (-i)
__device__ __forceinline__ cx cpos_i(cx a) { return mkcx(-a.y, a.x); }   // a * (+i)
__host__ __device__ constexpr int brev4(int t) {
    return ((t & 1) << 3) | ((t & 2) << 1) | ((t & 4) >> 1) | ((t & 8) >> 3);
}

#define CC1 0.9238795325112867f
#define SS1 0.3826834323650898f
#define RR2 0.7071067811865476f

template<bool HZ>
__device__ __forceinline__ void fft16_dif_r4(cx x[16]) {
    const cx W1 = mkcx( CC1, -SS1);
    const cx W2 = mkcx( RR2, -RR2);
    const cx W3 = mkcx( SS1, -CC1);
    const cx W6 = mkcx(-RR2, -RR2);
    const cx W9 = mkcx(-CC1,  SS1);
    #pragma unroll
    for (int n = 0; n < 4; ++n) {
        cx A, B, C, D;
        if (HZ) { A = x[n]; C = x[n]; B = x[n + 4]; D = x[n + 4]; }
        else {
            A = x[n] + x[n + 8];      C = x[n] - x[n + 8];
            B = x[n + 4] + x[n + 12]; D = x[n + 4] - x[n + 12];
        }
        cx s = A - B;
        cx nid = cneg_i(D);
        cx m = C + nid;
        cx p = C - nid;
        x[n] = A + B;
        if (n == 0)      { x[4] = s;            x[8]  = m;           x[12] = p; }
        else if (n == 1) { x[5] = cmul(s, W2);  x[9]  = cmul(m, W1); x[13] = cmul(p, W3); }
        else if (n == 2) { x[6] = cneg_i(s);    x[10] = cmul(m, W2); x[14] = cmul(p, W6); }
        else             { x[7] = cmul(s, W6);  x[11] = cmul(m, W3); x[15] = cmul(p, W9); }
    }
    #pragma unroll
    for (int q = 0; q < 16; q += 4) {
        cx a = x[q], b = x[q + 1], c = x[q + 2], d = x[q + 3];
        cx a1 = a + c, c1 = a - c;
        cx b1 = b + d, d1 = cneg_i(b - d);
        x[q]     = a1 + b1;
        x[q + 1] = a1 - b1;
        x[q + 2] = c1 + d1;
        x[q + 3] = c1 - d1;
    }
}

template<bool HALF_OUT>
__device__ __forceinline__ void fft16_dit_inv_r4(cx x[16]) {
    const cx V1 = mkcx( CC1, SS1);
    const cx V2 = mkcx( RR2, RR2);
    const cx V3 = mkcx( SS1, CC1);
    const cx V6 = mkcx(-RR2, RR2);
    #pragma unroll
    for (int q = 0; q < 16; q += 4) {
        cx a = x[q], b = x[q + 1], c = x[q + 2], d = x[q + 3];
        cx a1 = a + b, b1 = a - b;
        cx c1 = c + d, d1 = c - d;
        cx t = cpos_i(d1);
        x[q]     = a1 + c1;
        x[q + 2] = a1 - c1;
        x[q + 1] = b1 + t;
        x[q + 3] = b1 - t;
    }
    #pragma unroll
    for (int n = 0; n < 4; ++n) {
        cx t1, t2;
        if (n == 0)      { t1 = x[4];             t2 = x[12]; }
        else if (n == 1) { t1 = cmul(x[5],  V2);  t2 = cmul(x[13], V2); }
        else if (n == 2) { t1 = cpos_i(x[6]);     t2 = cpos_i(x[14]); }
        else             { t1 = cmul(x[7],  V6);  t2 = cmul(x[15], V6); }
        cx P = x[n] + t1, Q = x[n] - t1;
        cx R = x[n + 8] + t2, S = x[n + 8] - t2;
        cx t, u;
        if (n == 0)      { t = R;            u = S; }
        else if (n == 1) { t = cmul(R, V1);  u = cmul(S, V1); }
        else if (n == 2) { t = cmul(R, V2);  u = cmul(S, V2); }
        else             { t = cmul(R, V3);  u = cmul(S, V3); }
        cx iu = cpos_i(u);
        x[n]     = P + t;
        x[n + 4] = Q + iu;
        if (!HALF_OUT) {
            x[n + 8]  = P - t;
            x[n + 12] = Q - iu;
        }
    }
}

template<bool CONJ>
__device__ __forceinline__ void apply_tw(cx v[16], const cx tw[16]) {
    #pragma unroll
    for (int tau = 1; tau < 16; ++tau) {
        const int q = brev4(tau);
        v[q] = CONJ ? cmul_cj(v[q], tw[tau]) : cmul(v[q], tw[tau]);
    }
}

// twrow points at tw2lds + (t2&15); stride 16 per tau. Broadcast reads.
template<bool CONJ>
__device__ __forceinline__ void apply_tw_lds(cx v[16], const cx* twrow) {
    #pragma unroll
    for (int tau = 1; tau < 16; ++tau) {
        cx w = twrow[tau * 16];
        const int q = brev4(tau);
        v[q] = CONJ ? cmul_cj(v[q], w) : cmul(v[q], w);
    }
}

// ---- per-stage helpers (in-place per-thread; caller places sync) ----------
__device__ __forceinline__ void fwd_s1_store_hz(
    const cx vin[8], const cx tw[16], cx* d, int tid)
{
    cx x[16];
    #pragma unroll
    for (int t = 0; t < 8; ++t) x[t] = vin[t];
    fft16_dif_r4<true>(x);
    apply_tw<false>(x, tw);
    cx* base = d + fpad(tid);
    #pragma unroll
    for (int p = 0; p < 16; ++p) base[274 * p] = x[p];
}

__device__ __forceinline__ void fwd_s2(cx* d, int tid, const cx* tw2lds)
{
    cx v[16];
    cx* base = d + fpad(((tid >> 4) << 8) + (tid & 15));
    #pragma unroll
    for (int t = 0; t < 16; ++t) v[t] = base[17 * t];
    fft16_dif_r4<false>(v);
    apply_tw_lds<false>(v, tw2lds + (tid & 15));
    #pragma unroll
    for (int p = 0; p < 16; ++p) base[17 * p] = v[p];
}

// stage 3: keeps result in v (thread owns bins [tid*16, tid*16+16))
__device__ __forceinline__ void fwd_s3_keep(cx* d, int tid, cx v[16])
{
    cx* base = d + fpad(tid << 4);
    #pragma unroll
    for (int t = 0; t < 16; ++t) v[t] = base[t];
    fft16_dif_r4<false>(v);
    #pragma unroll
    for (int p = 0; p < 16; ++p) base[p] = v[p];
}

__device__ __forceinline__ void inv_s2(cx* d, int tid, const cx* tw2lds)
{
    cx v[16];
    cx* base = d + fpad(((tid >> 4) << 8) + (tid & 15));
    #pragma unroll
    for (int p = 0; p < 16; ++p) v[p] = base[17 * p];
    apply_tw_lds<true>(v, tw2lds + (tid & 15));
    fft16_dit_inv_r4<false>(v);
    #pragma unroll
    for (int t = 0; t < 16; ++t) base[17 * t] = v[t];
}

// inv stage 3 (lower half) fused with the u-gate: output stays in regs and
// goes straight to global at n = tid + 256*t (coalesced strided).
__device__ __forceinline__ void inv_s3_gate(
    const cx* d, int tid, const cx tw[16],
    const bf16 ua[8], const bf16 ub[8],
    bf16* __restrict__ g0, bf16* __restrict__ g1)
{
    cx v[16];
    const cx* base = d + fpad(tid);
    #pragma unroll
    for (int p = 0; p < 16; ++p) v[p] = base[274 * p];
    apply_tw<true>(v, tw);
    fft16_dit_inv_r4<true>(v);
    #pragma unroll
    for (int t = 0; t < 8; ++t) {
        const int n = tid + 256 * t;
        g0[n] = (bf16)(v[t].x * (float)ua[t]);
        g1[n] = (bf16)(v[t].y * (float)ub[t]);
    }
}

// pointwise using own fwd-s3 regs (v in: Z block; v out: Y block).
// Only the conjugate-partner block is read from LDS (thread 0: none).
__device__ __forceinline__ void pointwise_regs(
    const cx* d, int tid, const float4 a0pf[8], const float4 a1pf[8],
    cx v[16])
{
    auto pf = [](const float4* p, int i) -> cx {
        return (i & 1) ? mkcx(p[i >> 1].z, p[i >> 1].w)
                       : mkcx(p[i >> 1].x, p[i >> 1].y);
    };
    const int pbase = tid << 4;
    cx zm[16];
    if (tid == 0) {
        #pragma unroll
        for (int i = 0; i < 16; ++i) {
            const int p2 = (i < 2) ? i : (i ^ ((1 << (31 - __clz(i))) - 1));
            zm[i] = v[p2];                    // compile-time index
        }
    } else {
        const int mask = (1 << (31 - __clz(pbase))) - 1;
        const cx* zb2 = d + fpad((pbase ^ mask) - 15);
        #pragma unroll
        for (int i = 0; i < 16; ++i) zm[i] = zb2[15 - i];
    }
    #pragma unroll
    for (int i = 0; i < 16; ++i) {
        cx Zk = v[i];
        cx cjZm = mkcx(zm[i].x, -zm[i].y);
        cx V0 = Zk + cjZm;
        cx V1 = cneg_i(Zk - cjZm);
        v[i] = cmul(V0, pf(a0pf, i)) + cpos_i(cmul(V1, pf(a1pf, i)));
    }
}

// ---------------------------------------------------------------------------
// Forward FFT of packed (a_ch0, a_ch1) pair, unpack both real spectra in
// DIF order (conjugate-partner: p2 = p ^ (2^floor(log2 p) - 1)).
// A0 = c*(Wk + conj(Wm)), A1 = c*(-i)*(Wk - conj(Wm)), c = 0.25/4096.
// Wk comes from fwd-s3 registers; only Wm is read from LDS.
// ---------------------------------------------------------------------------
__global__ __launch_bounds__(256, 4) void fft_a_kernel(
    const float* a_t, cx* __restrict__ A0s, cx* A1s,
    const cx* __restrict__ Twd)
{
    __shared__ cx data[FFT_LDS_SZ];
    __shared__ cx tw2lds[256];
    const int tid = threadIdx.x;
    const int r = blockIdx.x;                      // pair index, ch = 2r

    cx tw[16];
    {
        const cx* Tr1 = Twd + (tid << 4);
        #pragma unroll
        for (int t = 1; t < 16; ++t) tw[t] = Tr1[t];
        tw2lds[(tid >> 4) * 16 + (tid & 15)] = Twd[(tid & 15) * 256 + (tid >> 4)];
    }

    const float* r0 = a_t + (size_t)(2 * r) * M_FFT;
    const float* r1 = r0 + M_FFT;
    cx v[16];
    #pragma unroll
    for (int t = 0; t < 16; ++t)
        v[t] = mkcx(r0[tid + 256 * t], r1[tid + 256 * t]);

    {   // stage 1 from registers
        fft16_dif_r4<false>(v);
        apply_tw<false>(v, tw);
        cx* base = data + fpad(tid);
        #pragma unroll
        for (int p = 0; p < 16; ++p) base[274 * p] = v[p];
    }
    __syncthreads();                      // cross-group: s1 -> s2
    fwd_s2(data, tid, tw2lds);
    WAVE_LDS_FENCE();                     // same-wave: s2 -> s3
    fwd_s3_keep(data, tid, v);
    __syncthreads();                      // cross-group: s3 -> partner unpack

    const float c = 0.25f / 4096.0f;
    const int base_i = tid << 4;
    cx* A0row = A0s + (size_t)r * 4096;
    cx* A1row = A1s + (size_t)r * 4096;
    cx wm[16];
    if (tid == 0) {
        #pragma unroll
        for (int i = 0; i < 16; ++i) {
            const int p2 = (i < 2) ? i : (i ^ ((1 << (31 - __clz(i))) - 1));
            wm[i] = v[p2];
        }
    } else {
        const int mask = (1 << (31 - __clz(base_i))) - 1;
        const cx* zb2 = data + fpad((base_i ^ mask) - 15);
        #pragma unroll
        for (int i = 0; i < 16; ++i) wm[i] = zb2[15 - i];
    }
    #pragma unroll
    for (int i = 0; i < 16; ++i) {
        cx cjWm = mkcx(wm[i].x, -wm[i].y);
        A0row[base_i + i] = c * (v[i] + cjWm);
        A1row[base_i + i] = c * cneg_i(v[i] - cjWm);
    }
}

// ---------------------------------------------------------------------------
// Conv kernel, 512 threads: each 256-thread HALF owns one chunk (batch
// 2bp+half of channel-pair r). TLP doubled at constant LDS: 16 waves/CU
// (was 8) -- the round-13 counters showed dependent-chain latency with
// VALUBusy 40% at 8 waves. A rows shared by both halves (same r, L1-hit).
// 4 barriers + 2 same-wave fences, as before.
// ---------------------------------------------------------------------------
__global__ __launch_bounds__(512, 4) void fft_conv_kernel(
    const bf16* __restrict__ v_t, const cx* __restrict__ A0s,
    const cx* __restrict__ A1s, const bf16* __restrict__ u_t,
    bf16* __restrict__ gated_t, const cx* __restrict__ Twd)
{
    __shared__ cx data[2][FFT_LDS_SZ];
    __shared__ cx tw2lds[256];
    const int tid  = threadIdx.x;
    const int half = tid >> 8;                // chunk index 0/1
    const int t2   = tid & 255;               // lane within chunk cohort
    const int bx = blockIdx.x;
    const int xcd  = bx & 7;
    const int slot = bx >> 3;                 // [0,192)
    const int bp   = slot & 1;
    const int r    = (slot >> 1) * 8 + xcd;   // [0,768), bijective
    const int ch   = 2 * r;
    const int b    = 2 * bp + half;           // this half's batch

    cx tw[16];
    {
        const cx* Tr1 = Twd + (t2 << 4);
        #pragma unroll
        for (int t = 1; t < 16; ++t) tw[t] = Tr1[t];
        if (tid < 256)
            tw2lds[(t2 >> 4) * 16 + (t2 & 15)] = Twd[(t2 & 15) * 256 + (t2 >> 4)];
    }

    // ---- forward stage 1: own chunk straight from global ----
    const bf16* z0 = v_t + ((size_t)(b * D1 + ch)) * N_SEQ;
    const bf16* z1 = z0 + N_SEQ;
    {
        cx w0[8];
        #pragma unroll
        for (int t = 0; t < 8; ++t)
            w0[t] = mkcx((float)z0[t2 + 256 * t], (float)z1[t2 + 256 * t]);
        fwd_s1_store_hz(w0, tw, data[half], t2);
    }
    __syncthreads();                      // 1: cross-group s1 -> s2

    fwd_s2(data[half], t2, tw2lds);
    WAVE_LDS_FENCE();                     // same-wave s2 -> s3

    // A rows (same r for both halves): issue before stage-3 compute.
    const int pbase = t2 << 4;
    float4 a0pf[8], a1pf[8];
    {
        const float4* A0p = (const float4*)(A0s + (size_t)r * 4096 + pbase);
        const float4* A1p = (const float4*)(A1s + (size_t)r * 4096 + pbase);
        #pragma unroll
        for (int i = 0; i < 8; ++i) { a0pf[i] = A0p[i]; a1pf[i] = A1p[i]; }
    }
    cx v[16];
    fwd_s3_keep(data[half], t2, v);
    __syncthreads();                      // 2: cross-group s3 -> pointwise

    // ---- pointwise (own Z from regs, partner from LDS; A in regs) ----
    pointwise_regs(data[half], t2, a0pf, a1pf, v);
    __syncthreads();                      // 3: partner reads done (cross-wave)
    fft16_dit_inv_r4<false>(v);
    {
        cx* base = data[half] + fpad(pbase);
        #pragma unroll
        for (int i = 0; i < 16; ++i) base[i] = v[i];
    }
    WAVE_LDS_FENCE();                     // same-wave inv1 -> inv2

    // u rows (strided layout matching inv-s3 ownership): issue before inv
    // stage 2 so the latency hides under it.
    const bf16* u0 = u_t + ((size_t)(b * D1 + ch)) * N_SEQ;
    const bf16* u1 = u0 + N_SEQ;
    bf16 ua[8], ub[8];
    #pragma unroll
    for (int t = 0; t < 8; ++t) {
        const int n = t2 + 256 * t;
        ua[t] = u0[n]; ub[t] = u1[n];
    }

    inv_s2(data[half], t2, tw2lds);
    __syncthreads();                      // 4: cross-group inv2 -> inv3

    bf16* g0 = gated_t + ((size_t)(b * D1 + ch)) * N_SEQ;
    bf16* g1 = g0 + N_SEQ;
    inv_s3_gate(data[half], t2, tw, ua, ub, g0, g1);
}

// ---------------------------------------------------------------------------
__global__ __launch_bounds__(256) void transpose_cs_kernel(
    const bf16* __restrict__ in, bf16* __restrict__ outp)
{
    __shared__ bf16 tile[64 * 68];
    const int c0 = blockIdx.x * 64;
    const int m0 = blockIdx.y * 64;
    const int b  = m0 >> 11;
    const int s0 = m0 & 2047;
    const int tid = threadIdx.x;
    const int cl = tid >> 4;
    const int sc = (tid & 15) * 4;
    #pragma unroll
    for (int p = 0; p < 4; ++p) {
        int c = p * 16 + cl;
        bf16x4 v = *(const bf16x4*)&in[((size_t)(b * D1 + c0 + c)) * N_SEQ + s0 + sc];
        *(bf16x4*)&tile[c * 68 + sc] = v;
    }
    __syncthreads();
    const int sl = tid >> 4;
    const int cc = (tid & 15) * 4;
    #pragma unroll
    for (int p = 0; p < 4; ++p) {
        int s = p * 16 + sl;
        bf16x4 o;
        #pragma unroll
        for (int j = 0; j < 4; ++j) o[j] = tile[(cc + j) * 68 + s];
        *(bf16x4*)&outp[((size_t)(m0 + s)) * D1 + c0 + cc] = o;
    }
}

// ---------------------------------------------------------------------------
extern "C" void kernel_launch(void* const* d_in, const int* in_sizes, int n_in,
                              void* d_out, int out_size, void* d_ws, size_t ws_size,
                              hipStream_t stream)
{
    const float* x  = (const float*)d_in[0];
    const float* Wu = (const float*)d_in[1];
    const float* bu = (const float*)d_in[2];
    const float* Wv = (const float*)d_in[3];
    const float* bv = (const float*)d_in[4];
    const float* Wo = (const float*)d_in[5];
    const float* bo = (const float*)d_in[6];
    const float* Wp = (const float*)d_in[7];
    const float* bp = (const float*)d_in[8];
    const float* Wl = (const float*)d_in[9];
    const float* bl = (const float*)d_in[10];
    const float* Wr = (const float*)d_in[11];
    const float* br = (const float*)d_in[12];
    float* out = (float*)d_out;

    float* ws      = (float*)d_ws;
    float* a_t     = ws;                       // 1536*4096 fp32; A1spec after fft_a
    float* A0spec  = a_t   + 6291456;          // 768 x 4096 cx
    float* sumsq   = A0spec + 6291456;         // 3 x 4096 fp32
    float* twd     = sumsq + 12288;            // 256 x 16 cx twiddle table
    bf16*  bfws    = (bf16*)(twd + 8192);
    bf16*  x_bf    = bfws;                     // 8192*512
    bf16*  w_bf    = x_bf    + 4194304;        // 5 x 786432: Wu,Wv,Wo,Wl,Wr
    bf16*  Wuv_bf  = w_bf;                     // stacked [Wu;Wv] 3072 x 512
    bf16*  Wo_bf   = w_bf    + 2 * 786432;
    bf16*  Wl_bf   = Wo_bf   + 786432;
    bf16*  Wr_bf   = Wl_bf   + 786432;
    bf16*  gA      = Wr_bf   + 786432;         // 4096*512
    bf16*  gB      = gA      + 2097152;        // 4096*512
    bf16*  u_t     = gB      + 2097152;        // 8192*1536 [b][c][s]
    bf16*  v_t     = u_t     + 12582912;       // 8192*1536 [b][c][s]
    bf16*  gated_t = v_t     + 12582912;       // 8192*1536 [b][c][s]
    bf16*  gated   = gated_t + 12582912;       // 8192*1536 [m][c]

    dim3 blk(256);

    // x/w converts + sumsq zero + rpe input layer + twiddle table
    f2b_all_kernel<<<4096 + 5 * 768 + 12 + 4096 + 16, blk, 0, stream>>>(
        x, Wu, Wv, Wo, Wl, Wr, Wp, bp, x_bf, w_bf, sumsq, gA, twd);

    gemm_bf16<MODE_SILU_UV, 128, bf16><<<dim3(24, 64), blk, 0, stream>>>(
        x_bf, Wuv_bf, bu, bv, u_t, v_t, 8192, 2 * D1, ED, nullptr, nullptr);

    // RPE MLP: srms folded into GEMM epilogues via row-scale commutation.
    bf16* gin = gA;
    bf16* gout = gB;
    for (int i = 0; i < 3; ++i) {
        const float* sin_p = (i == 0) ? nullptr : sumsq + (size_t)(i - 1) * 4096;
        gemm_bf16<MODE_RPE, 64, bf16><<<dim3(8, 32), blk, 0, stream>>>(
            gin, Wl_bf + (size_t)i * ED * ED, bl + (size_t)i * ED, nullptr,
            gout, nullptr, 4096, ED, ED, sin_p, sumsq + (size_t)i * 4096);
        bf16* t = gin; gin = gout; gout = t;
    }
    gemm_bf16<MODE_AT, 64, float><<<dim3(24, 32), blk, 0, stream>>>(
        gin, Wr_bf, br, nullptr, a_t, nullptr, 4096, D1, ED,
        sumsq + 2 * 4096, nullptr);

    fft_a_kernel<<<768, blk, 0, stream>>>(
        a_t, (cx*)A0spec, (cx*)a_t, (const cx*)twd);
    fft_conv_kernel<<<1536, dim3(512), 0, stream>>>(
        v_t, (const cx*)A0spec, (const cx*)a_t, u_t, gated_t, (const cx*)twd);

    transpose_cs_kernel<<<dim3(24, 128), blk, 0, stream>>>(gated_t, gated);

    gemm_bf16<MODE_PLAIN, 64, float><<<dim3(8, 64), blk, 0, stream>>>(
        gated, Wo_bf, bo, nullptr, out, nullptr, 8192, ED, D1,
        nullptr, nullptr);
}

// Round 15
// 349.028 us; speedup vs baseline: 1.0672x; 1.0672x over previous
//
#include <hip/hip_runtime.h>

#define N_SEQ 2048
#define M_FFT 4096
#define D1    1536
#define NH    8
#define HD    192
#define ED    512

typedef __bf16 bf16;
typedef __bf16 bf16x4 __attribute__((ext_vector_type(4)));
typedef __bf16 bf16x8 __attribute__((ext_vector_type(8)));
typedef float  floatx4 __attribute__((ext_vector_type(4)));
typedef float  cx __attribute__((ext_vector_type(2)));   // complex as packed fp32

enum { MODE_PLAIN = 0, MODE_SILU_UV = 1, MODE_AT = 3, MODE_RPE = 4 };

__device__ __forceinline__ void gload16(const void* g, void* l) {
    __builtin_amdgcn_global_load_lds(
        (const __attribute__((address_space(1))) void*)g,
        (__attribute__((address_space(3))) void*)l, 16, 0, 0);
}

// same-wave LDS hand-off: commit prior ds_writes + compiler fence.
// Valid only when producer and consumer threads are in the same wave
// (DS ops of a wave execute in order).
#define WAVE_LDS_FENCE() asm volatile("s_waitcnt lgkmcnt(0)" ::: "memory")

// ---------------------------------------------------------------------------
// bf16 MFMA GEMM, depth-3 pipeline with COUNTED vmcnt (T4), BN-templated,
// + T2 granule-XOR LDS swizzle + T5 setprio.
// SILU_UV / AT epilogues transpose through LDS (reusing dead staging bufs).
// ---------------------------------------------------------------------------
template<int MODE, int BN, typename OutT>
__global__ __launch_bounds__(256) void gemm_bf16(
    const bf16* __restrict__ A, const bf16* __restrict__ Bw,
    const float* __restrict__ bias, const float* __restrict__ bias2,
    OutT* __restrict__ C, OutT* __restrict__ C2,
    int M, int Nc, int K,
    const float* __restrict__ scale_in, float* __restrict__ sumsq_out)
{
    constexpr int NJ  = BN / 32;           // n-fragments per wave (4 or 2)
    constexpr int ASZ = 3 * 128 * 32;
    constexpr int BSZ = 3 * BN * 32;
    __shared__ __align__(16) bf16 smem[ASZ + BSZ];
    bf16* As = smem;
    bf16* Bs = smem + ASZ;

    const int tid  = threadIdx.x;
    const int row0 = blockIdx.y * 128;
    const int col0 = blockIdx.x * BN;
    const int wid  = tid >> 6;
    const int lane = tid & 63;
    const int lm   = lane & 15;
    const int lk   = lane >> 4;
    const int wm   = wid >> 1;
    const int wn   = wid & 1;
    const int ldrow  = tid >> 2;
    // T2 write-side: source granule = (tid&3) ^ ((row>>1)&3), row = tid>>2
    const int ldcol8 = (((tid & 3) ^ ((tid >> 3) & 3))) * 8;
    // T2 read-side: granule = lk ^ ((row>>1)&3) = lk ^ ((lm>>1)&3)
    const int gsw = (lk ^ ((lm >> 1) & 3)) * 8;

    floatx4 acc[4][NJ] = {};

    const bf16* Ag = A  + ((size_t)(row0 + ldrow)) * K + ldcol8;
    const bf16* Bg = Bw + ((size_t)(col0 + ldrow)) * K + ldcol8;
    const int woff = (wid * 16) * 32;

    auto stage = [&](int t, int buf) {
        const int k0 = t << 5;
        gload16(Ag + k0, &As[buf * (128 * 32) + woff]);
        gload16(Ag + (size_t)64 * K + k0, &As[buf * (128 * 32) + woff + 64 * 32]);
        gload16(Bg + k0, &Bs[buf * (BN * 32) + woff]);
        if constexpr (BN == 128)
            gload16(Bg + (size_t)64 * K + k0, &Bs[buf * (BN * 32) + woff + 64 * 32]);
    };
    auto compute = [&](int buf) {
        bf16x8 af[4], bfr[NJ];
        #pragma unroll
        for (int mi = 0; mi < 4; ++mi)
            af[mi] = *(const bf16x8*)&As[buf * (128 * 32) + (wm * 64 + mi * 16 + lm) * 32 + gsw];
        #pragma unroll
        for (int nj = 0; nj < NJ; ++nj)
            bfr[nj] = *(const bf16x8*)&Bs[buf * (BN * 32) + (wn * (BN / 2) + nj * 16 + lm) * 32 + gsw];
        __builtin_amdgcn_s_setprio(1);                 // T5
        #pragma unroll
        for (int mi = 0; mi < 4; ++mi)
            #pragma unroll
            for (int nj = 0; nj < NJ; ++nj)
                acc[mi][nj] = __builtin_amdgcn_mfma_f32_16x16x32_bf16(
                    af[mi], bfr[nj], acc[mi][nj], 0, 0, 0);
        __builtin_amdgcn_s_setprio(0);
    };

    const int nt = K >> 5;           // 16 or 48
    stage(0, 0);
    stage(1, 1);
    int sb = 2, cb = 0;
    for (int t = 0; t < nt; ++t) {
        __builtin_amdgcn_s_barrier();          // A: compute(t-1) done everywhere
        __builtin_amdgcn_sched_barrier(0);
        if (t + 2 < nt) {
            stage(t + 2, sb);
            if (++sb == 3) sb = 0;
        }
        // own tile-t loads complete; next two tiles stay in flight
        if (t < nt - 2) {
            if constexpr (BN == 128) asm volatile("s_waitcnt vmcnt(8)" ::: "memory");
            else                     asm volatile("s_waitcnt vmcnt(6)" ::: "memory");
        } else if (t == nt - 2) {
            if constexpr (BN == 128) asm volatile("s_waitcnt vmcnt(4)" ::: "memory");
            else                     asm volatile("s_waitcnt vmcnt(3)" ::: "memory");
        } else {
            asm volatile("s_waitcnt vmcnt(0)" ::: "memory");
        }
        __builtin_amdgcn_s_barrier();          // B: tile t fully in LDS (all waves)
        __builtin_amdgcn_sched_barrier(0);
        compute(cb);
        if (++cb == 3) cb = 0;
    }

    const float* bs = bias;
    OutT* dst = C;
    int cadj = 0;
    if (MODE == MODE_SILU_UV && col0 >= D1) { bs = bias2; dst = C2; cadj = D1; }

    float bcol[NJ];
    #pragma unroll
    for (int nj = 0; nj < NJ; ++nj)
        bcol[nj] = bs[col0 - cadj + wn * (BN / 2) + nj * 16 + lm];

    if (MODE == MODE_RPE) {
        #pragma unroll
        for (int mi = 0; mi < 4; ++mi) {
            #pragma unroll
            for (int r = 0; r < 4; ++r) {
                const int row = row0 + wm * 64 + mi * 16 + lk * 4 + r;
                float sc = 1.0f;
                if (scale_in)
                    sc = 1.0f / (sqrtf(scale_in[row]) * 0.04419417382415922f + 1e-8f);
                float ssq = 0.0f;
                #pragma unroll
                for (int nj = 0; nj < NJ; ++nj) {
                    const int col = col0 + wn * (BN / 2) + nj * 16 + lm;
                    float val = acc[mi][nj][r] * sc + bcol[nj];
                    ssq += val * val;
                    ((bf16*)C)[(size_t)row * Nc + col] = (bf16)fmaxf(val, 0.0f);
                }
                ssq += __shfl_xor(ssq, 1, 64);
                ssq += __shfl_xor(ssq, 2, 64);
                ssq += __shfl_xor(ssq, 4, 64);
                ssq += __shfl_xor(ssq, 8, 64);
                if (lm == 0) atomicAdd(&sumsq_out[row], ssq);
            }
        }
        return;
    }

    if (MODE == MODE_SILU_UV) {
        // ---- transpose-through-LDS coalesced store (128 x 128 tile) ----
        constexpr int TP = 136;                 // row pad: 16B-aligned rows
        bf16* T = smem;                         // 128*136*2 = 34816 B <= 48K
        __syncthreads();                        // K-loop LDS reads done
        #pragma unroll
        for (int mi = 0; mi < 4; ++mi) {
            const int rl = wm * 64 + mi * 16 + lk * 4;
            #pragma unroll
            for (int nj = 0; nj < NJ; ++nj) {
                const int cl = wn * 64 + nj * 16 + lm;
                bf16x4 o;
                #pragma unroll
                for (int r = 0; r < 4; ++r) {
                    float val = acc[mi][nj][r] + bcol[nj];
                    val = val * __fdividef(1.0f, 1.0f + __expf(-val));
                    o[r] = (bf16)val;
                }
                *(bf16x4*)&T[cl * TP + rl] = o;
            }
        }
        __syncthreads();
        const int b  = row0 >> 11;
        const int s0 = row0 & 2047;
        #pragma unroll
        for (int j = 0; j < 8; ++j) {
            const int idx = j * 256 + tid;      // [0, 2048)
            const int sc  = (idx & 15) * 8;     // s-chunk (16 consecutive tids)
            const int c   = idx >> 4;           // column 0..127
            bf16x8 o = *(const bf16x8*)&T[c * TP + sc];
            *(bf16x8*)&((bf16*)dst)[((size_t)(b * D1 + col0 - cadj + c)) * N_SEQ + s0 + sc] = o;
        }
        return;
    }

    if (MODE == MODE_AT) {
        // ---- transpose-through-LDS coalesced fp32 store (64 x 128 tile) ----
        constexpr int TP = 132;                 // fp32 row pad (16B-aligned)
        float* Tf = (float*)smem;               // 64*132*4 = 33792 B <= 36864
        __syncthreads();
        #pragma unroll
        for (int mi = 0; mi < 4; ++mi) {
            const int rbase = row0 + wm * 64 + mi * 16 + lk * 4;
            const int rl    = wm * 64 + mi * 16 + lk * 4;
            float sc[4];
            #pragma unroll
            for (int r = 0; r < 4; ++r)
                sc[r] = scale_in
                    ? 1.0f / (sqrtf(scale_in[rbase + r]) * 0.04419417382415922f + 1e-8f)
                    : 1.0f;
            #pragma unroll
            for (int nj = 0; nj < NJ; ++nj) {
                const int cl = wn * (BN / 2) + nj * 16 + lm;
                float4 o;
                o.x = acc[mi][nj][0] * sc[0] + bcol[nj];
                o.y = acc[mi][nj][1] * sc[1] + bcol[nj];
                o.z = acc[mi][nj][2] * sc[2] + bcol[nj];
                o.w = acc[mi][nj][3] * sc[3] + bcol[nj];
                *(float4*)&Tf[cl * TP + rl] = o;
            }
        }
        __syncthreads();
        #pragma unroll
        for (int j = 0; j < 8; ++j) {
            const int idx = j * 256 + tid;      // [0, 2048)
            const int rc  = (idx & 31) * 4;     // row-chunk (32 consecutive tids)
            const int c   = idx >> 5;           // column 0..63
            float4 o = *(const float4*)&Tf[c * TP + rc];
            *(float4*)&((float*)C)[(size_t)(col0 + c) * M + row0 + rc] = o;
        }
        return;
    }

    // MODE_PLAIN: row-major contiguous store (already coalesced enough)
    #pragma unroll
    for (int mi = 0; mi < 4; ++mi) {
        const int rbase = row0 + wm * 64 + mi * 16 + lk * 4;
        #pragma unroll
        for (int nj = 0; nj < NJ; ++nj) {
            const int col = col0 + wn * (BN / 2) + nj * 16 + lm;
            #pragma unroll
            for (int r = 0; r < 4; ++r) {
                float val = acc[mi][nj][r] + bcol[nj];
                C[(size_t)(rbase + r) * Nc + col] = (OutT)val;
            }
        }
    }
}

// ---------------------------------------------------------------------------
// mega-prologue: x convert + 5 weight converts + sumsq zero +
// RPE input layer w/ srms + FFT twiddle table (256 x 16 cx)
// ---------------------------------------------------------------------------
__global__ __launch_bounds__(256) void f2b_all_kernel(
    const float* __restrict__ x,  const float* __restrict__ s0,
    const float* __restrict__ s1, const float* __restrict__ s2,
    const float* __restrict__ s3, const float* __restrict__ s4,
    const float* __restrict__ Wp, const float* __restrict__ bp,
    bf16* __restrict__ x_bf, bf16* __restrict__ w_bf,
    float* __restrict__ sumsq, bf16* __restrict__ g0,
    float* __restrict__ twd)
{
    const int bid = blockIdx.x;
    const int tid = threadIdx.x;
    __shared__ float red[4];

    if (bid < 7936) {
        const float* src;
        bf16* dst;
        size_t off;
        if (bid < 4096) {
            src = x; dst = x_bf; off = (size_t)bid * 1024;
        } else {
            int t = bid - 4096;
            int seg = t / 768;
            src = seg == 0 ? s0 : seg == 1 ? s1 : seg == 2 ? s2
                : seg == 3 ? s3 : s4;
            dst = w_bf + (size_t)seg * 786432;
            off = (size_t)(t % 768) * 1024;
        }
        size_t i = off + (size_t)tid * 4;
        float4 f = *(const float4*)(src + i);
        union { bf16 h[4]; short4 s; } u4;
        u4.h[0] = (bf16)f.x; u4.h[1] = (bf16)f.y;
        u4.h[2] = (bf16)f.z; u4.h[3] = (bf16)f.w;
        *(short4*)(dst + i) = u4.s;
    } else if (bid < 7948) {
        size_t i = (size_t)(bid - 7936) * 1024 + (size_t)tid * 4;
        *(float4*)(sumsq + i) = make_float4(0.f, 0.f, 0.f, 0.f);
    } else if (bid < 12044) {
        const int j = bid - 7948;
        float idxv = (j < N_SEQ) ? (float)j
                                 : (j == N_SEQ ? 0.0f : (float)(j - 2 * N_SEQ));
        float h1 = idxv * Wp[tid] + bp[tid];
        float h2 = idxv * Wp[tid + 256] + bp[tid + 256];
        float ss = h1 * h1 + h2 * h2;
        #pragma unroll
        for (int off = 32; off > 0; off >>= 1) ss += __shfl_down(ss, off, 64);
        if ((tid & 63) == 0) red[tid >> 6] = ss;
        __syncthreads();
        float tot = red[0] + red[1] + red[2] + red[3];
        float scale = 1.0f / (sqrtf(tot) * 0.04419417382415922f + 1e-8f);
        g0[(size_t)j * ED + tid]       = (bf16)fmaxf(h1 * scale, 0.0f);
        g0[(size_t)j * ED + tid + 256] = (bf16)fmaxf(h2 * scale, 0.0f);
    } else {
        const int idx = (bid - 12044) * 256 + tid;    // [0, 4096)
        const int j = idx >> 4, tau = idx & 15;
        float sA, cA;
        __sincosf(-6.283185307179586f * (float)(j * tau) * (1.0f / 4096.0f),
                  &sA, &cA);
        cx w; w.x = cA; w.y = sA;
        ((cx*)twd)[idx] = w;
    }
}

// ---------------------------------------------------------------------------
// Radix-16 FFT, radix-4 butterflies, packed-fp32 complex.
// LDS addressing: fpad(base + s*t) = fpad(base) + s'*t  (256->274, 16->17, 1->1)
// Stage-1/inv-3 twiddle row in REGISTERS (inverse = conjugate);
// stage-2/inv-2 rows (16 distinct) in a 2 KB LDS broadcast table.
// SYNC: s2->s3 and inv1->inv2 are same-wave hand-offs (WAVE_LDS_FENCE).
// ---------------------------------------------------------------------------
#define FFT_LDS_SZ 4381

__device__ __forceinline__ int fpad(int i) { return i + (i >> 4) + 2 * (i >> 8); }

__device__ __forceinline__ cx mkcx(float a, float b) { cx r; r.x = a; r.y = b; return r; }
__device__ __forceinline__ cx cmul(cx a, cx b) {
    cx br = mkcx(-b.y, b.x);
    return a.xx * b + a.yy * br;
}
__device__ __forceinline__ cx cmul_cj(cx a, cx b) {      // a * conj(b)
    cx bc = mkcx(b.x, -b.y);
    cx br = mkcx(b.y, b.x);
    return a.xx * bc + a.yy * br;
}
__device__ __forceinline__ cx cneg_i(cx a) { return mkcx(a.y, -a.x); }   // a * (-i)
__device__ __forceinline__ cx cpos_i(cx a) { return mkcx(-a.y, a.x); }   // a * (+i)
__host__ __device__ constexpr int brev4(int t) {
    return ((t & 1) << 3) | ((t & 2) << 1) | ((t & 4) >> 1) | ((t & 8) >> 3);
}

#define CC1 0.9238795325112867f
#define SS1 0.3826834323650898f
#define RR2 0.7071067811865476f

template<bool HZ>
__device__ __forceinline__ void fft16_dif_r4(cx x[16]) {
    const cx W1 = mkcx( CC1, -SS1);
    const cx W2 = mkcx( RR2, -RR2);
    const cx W3 = mkcx( SS1, -CC1);
    const cx W6 = mkcx(-RR2, -RR2);
    const cx W9 = mkcx(-CC1,  SS1);
    #pragma unroll
    for (int n = 0; n < 4; ++n) {
        cx A, B, C, D;
        if (HZ) { A = x[n]; C = x[n]; B = x[n + 4]; D = x[n + 4]; }
        else {
            A = x[n] + x[n + 8];      C = x[n] - x[n + 8];
            B = x[n + 4] + x[n + 12]; D = x[n + 4] - x[n + 12];
        }
        cx s = A - B;
        cx nid = cneg_i(D);
        cx m = C + nid;
        cx p = C - nid;
        x[n] = A + B;
        if (n == 0)      { x[4] = s;            x[8]  = m;           x[12] = p; }
        else if (n == 1) { x[5] = cmul(s, W2);  x[9]  = cmul(m, W1); x[13] = cmul(p, W3); }
        else if (n == 2) { x[6] = cneg_i(s);    x[10] = cmul(m, W2); x[14] = cmul(p, W6); }
        else             { x[7] = cmul(s, W6);  x[11] = cmul(m, W3); x[15] = cmul(p, W9); }
    }
    #pragma unroll
    for (int q = 0; q < 16; q += 4) {
        cx a = x[q], b = x[q + 1], c = x[q + 2], d = x[q + 3];
        cx a1 = a + c, c1 = a - c;
        cx b1 = b + d, d1 = cneg_i(b - d);
        x[q]     = a1 + b1;
        x[q + 1] = a1 - b1;
        x[q + 2] = c1 + d1;
        x[q + 3] = c1 - d1;
    }
}

template<bool HALF_OUT>
__device__ __forceinline__ void fft16_dit_inv_r4(cx x[16]) {
    const cx V1 = mkcx( CC1, SS1);
    const cx V2 = mkcx( RR2, RR2);
    const cx V3 = mkcx( SS1, CC1);
    const cx V6 = mkcx(-RR2, RR2);
    #pragma unroll
    for (int q = 0; q < 16; q += 4) {
        cx a = x[q], b = x[q + 1], c = x[q + 2], d = x[q + 3];
        cx a1 = a + b, b1 = a - b;
        cx c1 = c + d, d1 = c - d;
        cx t = cpos_i(d1);
        x[q]     = a1 + c1;
        x[q + 2] = a1 - c1;
        x[q + 1] = b1 + t;
        x[q + 3] = b1 - t;
    }
    #pragma unroll
    for (int n = 0; n < 4; ++n) {
        cx t1, t2;
        if (n == 0)      { t1 = x[4];             t2 = x[12]; }
        else if (n == 1) { t1 = cmul(x[5],  V2);  t2 = cmul(x[13], V2); }
        else if (n == 2) { t1 = cpos_i(x[6]);     t2 = cpos_i(x[14]); }
        else             { t1 = cmul(x[7],  V6);  t2 = cmul(x[15], V6); }
        cx P = x[n] + t1, Q = x[n] - t1;
        cx R = x[n + 8] + t2, S = x[n + 8] - t2;
        cx t, u;
        if (n == 0)      { t = R;            u = S; }
        else if (n == 1) { t = cmul(R, V1);  u = cmul(S, V1); }
        else if (n == 2) { t = cmul(R, V2);  u = cmul(S, V2); }
        else             { t = cmul(R, V3);  u = cmul(S, V3); }
        cx iu = cpos_i(u);
        x[n]     = P + t;
        x[n + 4] = Q + iu;
        if (!HALF_OUT) {
            x[n + 8]  = P - t;
            x[n + 12] = Q - iu;
        }
    }
}

template<bool CONJ>
__device__ __forceinline__ void apply_tw(cx v[16], const cx tw[16]) {
    #pragma unroll
    for (int tau = 1; tau < 16; ++tau) {
        const int q = brev4(tau);
        v[q] = CONJ ? cmul_cj(v[q], tw[tau]) : cmul(v[q], tw[tau]);
    }
}

// twrow points at tw2lds + (t2&15); stride 16 per tau. Broadcast reads.
template<bool CONJ>
__device__ __forceinline__ void apply_tw_lds(cx v[16], const cx* twrow) {
    #pragma unroll
    for (int tau = 1; tau < 16; ++tau) {
        cx w = twrow[tau * 16];
        const int q = brev4(tau);
        v[q] = CONJ ? cmul_cj(v[q], w) : cmul(v[q], w);
    }
}

// ---- per-stage helpers (in-place per-thread; caller places sync) ----------
__device__ __forceinline__ void fwd_s1_store_hz(
    const cx vin[8], const cx tw[16], cx* d, int tid)
{
    cx x[16];
    #pragma unroll
    for (int t = 0; t < 8; ++t) x[t] = vin[t];
    fft16_dif_r4<true>(x);
    apply_tw<false>(x, tw);
    cx* base = d + fpad(tid);
    #pragma unroll
    for (int p = 0; p < 16; ++p) base[274 * p] = x[p];
}

__device__ __forceinline__ void fwd_s2(cx* d, int tid, const cx* tw2lds)
{
    cx v[16];
    cx* base = d + fpad(((tid >> 4) << 8) + (tid & 15));
    #pragma unroll
    for (int t = 0; t < 16; ++t) v[t] = base[17 * t];
    fft16_dif_r4<false>(v);
    apply_tw_lds<false>(v, tw2lds + (tid & 15));
    #pragma unroll
    for (int p = 0; p < 16; ++p) base[17 * p] = v[p];
}

// stage 3: keeps result in v (thread owns bins [tid*16, tid*16+16))
__device__ __forceinline__ void fwd_s3_keep(cx* d, int tid, cx v[16])
{
    cx* base = d + fpad(tid << 4);
    #pragma unroll
    for (int t = 0; t < 16; ++t) v[t] = base[t];
    fft16_dif_r4<false>(v);
    #pragma unroll
    for (int p = 0; p < 16; ++p) base[p] = v[p];
}

__device__ __forceinline__ void inv_s2(cx* d, int tid, const cx* tw2lds)
{
    cx v[16];
    cx* base = d + fpad(((tid >> 4) << 8) + (tid & 15));
    #pragma unroll
    for (int p = 0; p < 16; ++p) v[p] = base[17 * p];
    apply_tw_lds<true>(v, tw2lds + (tid & 15));
    fft16_dit_inv_r4<false>(v);
    #pragma unroll
    for (int t = 0; t < 16; ++t) base[17 * t] = v[t];
}

// inv stage 3 (lower half) fused with the u-gate: output stays in regs and
// goes straight to global at n = tid + 256*t (coalesced strided).
__device__ __forceinline__ void inv_s3_gate(
    const cx* d, int tid, const cx tw[16],
    const bf16 ua[8], const bf16 ub[8],
    bf16* __restrict__ g0, bf16* __restrict__ g1)
{
    cx v[16];
    const cx* base = d + fpad(tid);
    #pragma unroll
    for (int p = 0; p < 16; ++p) v[p] = base[274 * p];
    apply_tw<true>(v, tw);
    fft16_dit_inv_r4<true>(v);
    #pragma unroll
    for (int t = 0; t < 8; ++t) {
        const int n = tid + 256 * t;
        g0[n] = (bf16)(v[t].x * (float)ua[t]);
        g1[n] = (bf16)(v[t].y * (float)ub[t]);
    }
}

// pointwise using own fwd-s3 regs (v in: Z block; v out: Y block).
// A spectra read DIRECTLY from global (L2-warm) inline with the FMAs --
// no long-lived register prefetch (keeps peak VGPR under the 128 cap at
// 512 threads; 16 waves/CU of TLP cover the load latency).
__device__ __forceinline__ void pointwise_direct(
    const cx* d, int tid, const cx* __restrict__ A0p,
    const cx* __restrict__ A1p, cx v[16])
{
    const int pbase = tid << 4;
    cx zm[16];
    if (tid == 0) {
        #pragma unroll
        for (int i = 0; i < 16; ++i) {
            const int p2 = (i < 2) ? i : (i ^ ((1 << (31 - __clz(i))) - 1));
            zm[i] = v[p2];                    // compile-time index
        }
    } else {
        const int mask = (1 << (31 - __clz(pbase))) - 1;
        const cx* zb2 = d + fpad((pbase ^ mask) - 15);
        #pragma unroll
        for (int i = 0; i < 16; ++i) zm[i] = zb2[15 - i];
    }
    #pragma unroll
    for (int i = 0; i < 16; ++i) {
        cx a0 = A0p[i];
        cx a1 = A1p[i];
        cx Zk = v[i];
        cx cjZm = mkcx(zm[i].x, -zm[i].y);
        cx V0 = Zk + cjZm;
        cx V1 = cneg_i(Zk - cjZm);
        v[i] = cmul(V0, a0) + cpos_i(cmul(V1, a1));
    }
}

// ---------------------------------------------------------------------------
// Forward FFT of packed (a_ch0, a_ch1) pair, unpack both real spectra in
// DIF order (conjugate-partner: p2 = p ^ (2^floor(log2 p) - 1)).
// A0 = c*(Wk + conj(Wm)), A1 = c*(-i)*(Wk - conj(Wm)), c = 0.25/4096.
// Wk comes from fwd-s3 registers; only Wm is read from LDS.
// ---------------------------------------------------------------------------
__global__ __launch_bounds__(256, 4) void fft_a_kernel(
    const float* a_t, cx* __restrict__ A0s, cx* A1s,
    const cx* __restrict__ Twd)
{
    __shared__ cx data[FFT_LDS_SZ];
    __shared__ cx tw2lds[256];
    const int tid = threadIdx.x;
    const int r = blockIdx.x;                      // pair index, ch = 2r

    cx tw[16];
    {
        const cx* Tr1 = Twd + (tid << 4);
        #pragma unroll
        for (int t = 1; t < 16; ++t) tw[t] = Tr1[t];
        tw2lds[(tid >> 4) * 16 + (tid & 15)] = Twd[(tid & 15) * 256 + (tid >> 4)];
    }

    const float* r0 = a_t + (size_t)(2 * r) * M_FFT;
    const float* r1 = r0 + M_FFT;
    cx v[16];
    #pragma unroll
    for (int t = 0; t < 16; ++t)
        v[t] = mkcx(r0[tid + 256 * t], r1[tid + 256 * t]);

    {   // stage 1 from registers
        fft16_dif_r4<false>(v);
        apply_tw<false>(v, tw);
        cx* base = data + fpad(tid);
        #pragma unroll
        for (int p = 0; p < 16; ++p) base[274 * p] = v[p];
    }
    __syncthreads();                      // cross-group: s1 -> s2
    fwd_s2(data, tid, tw2lds);
    WAVE_LDS_FENCE();                     // same-wave: s2 -> s3
    fwd_s3_keep(data, tid, v);
    __syncthreads();                      // cross-group: s3 -> partner unpack

    const float c = 0.25f / 4096.0f;
    const int base_i = tid << 4;
    cx* A0row = A0s + (size_t)r * 4096;
    cx* A1row = A1s + (size_t)r * 4096;
    cx wm[16];
    if (tid == 0) {
        #pragma unroll
        for (int i = 0; i < 16; ++i) {
            const int p2 = (i < 2) ? i : (i ^ ((1 << (31 - __clz(i))) - 1));
            wm[i] = v[p2];
        }
    } else {
        const int mask = (1 << (31 - __clz(base_i))) - 1;
        const cx* zb2 = data + fpad((base_i ^ mask) - 15);
        #pragma unroll
        for (int i = 0; i < 16; ++i) wm[i] = zb2[15 - i];
    }
    #pragma unroll
    for (int i = 0; i < 16; ++i) {
        cx cjWm = mkcx(wm[i].x, -wm[i].y);
        A0row[base_i + i] = c * (v[i] + cjWm);
        A1row[base_i + i] = c * cneg_i(v[i] - cjWm);
    }
}

// ---------------------------------------------------------------------------
// Conv kernel, 512 threads: each 256-thread HALF owns one chunk (batch
// 2bp+half of channel-pair r). 16 waves/CU at 2 blocks/CU (LDS cap).
// __launch_bounds__(512, 2): 128-VGPR budget -- round-14's (512,4)
// forced a 64-VGPR cap and catastrophic scratch spills (WRITE_SIZE 8x).
// A spectra read directly in pointwise (no 64-VGPR prefetch).
// 4 barriers + 2 same-wave fences.
// ---------------------------------------------------------------------------
__global__ __launch_bounds__(512, 2) void fft_conv_kernel(
    const bf16* __restrict__ v_t, const cx* __restrict__ A0s,
    const cx* __restrict__ A1s, const bf16* __restrict__ u_t,
    bf16* __restrict__ gated_t, const cx* __restrict__ Twd)
{
    __shared__ cx data[2][FFT_LDS_SZ];
    __shared__ cx tw2lds[256];
    const int tid  = threadIdx.x;
    const int half = tid >> 8;                // chunk index 0/1
    const int t2   = tid & 255;               // lane within chunk cohort
    const int bx = blockIdx.x;
    const int xcd  = bx & 7;
    const int slot = bx >> 3;                 // [0,192)
    const int bp   = slot & 1;
    const int r    = (slot >> 1) * 8 + xcd;   // [0,768), bijective
    const int ch   = 2 * r;
    const int b    = 2 * bp + half;           // this half's batch

    cx tw[16];
    {
        const cx* Tr1 = Twd + (t2 << 4);
        #pragma unroll
        for (int t = 1; t < 16; ++t) tw[t] = Tr1[t];
        if (tid < 256)
            tw2lds[(t2 >> 4) * 16 + (t2 & 15)] = Twd[(t2 & 15) * 256 + (t2 >> 4)];
    }

    // ---- forward stage 1: own chunk straight from global ----
    const bf16* z0 = v_t + ((size_t)(b * D1 + ch)) * N_SEQ;
    const bf16* z1 = z0 + N_SEQ;
    {
        cx w0[8];
        #pragma unroll
        for (int t = 0; t < 8; ++t)
            w0[t] = mkcx((float)z0[t2 + 256 * t], (float)z1[t2 + 256 * t]);
        fwd_s1_store_hz(w0, tw, data[half], t2);
    }
    __syncthreads();                      // 1: cross-group s1 -> s2

    fwd_s2(data[half], t2, tw2lds);
    WAVE_LDS_FENCE();                     // same-wave s2 -> s3

    cx v[16];
    fwd_s3_keep(data[half], t2, v);
    __syncthreads();                      // 2: cross-group s3 -> pointwise

    // ---- pointwise (own Z from regs, partner from LDS, A direct) ----
    const int pbase = t2 << 4;
    pointwise_direct(data[half], t2,
                     A0s + (size_t)r * 4096 + pbase,
                     A1s + (size_t)r * 4096 + pbase, v);
    __syncthreads();                      // 3: partner reads done (cross-wave)
    fft16_dit_inv_r4<false>(v);
    {
        cx* base = data[half] + fpad(pbase);
        #pragma unroll
        for (int i = 0; i < 16; ++i) base[i] = v[i];
    }
    WAVE_LDS_FENCE();                     // same-wave inv1 -> inv2

    // u rows (strided layout matching inv-s3 ownership): issue before inv
    // stage 2 so the latency hides under it.
    const bf16* u0 = u_t + ((size_t)(b * D1 + ch)) * N_SEQ;
    const bf16* u1 = u0 + N_SEQ;
    bf16 ua[8], ub[8];
    #pragma unroll
    for (int t = 0; t < 8; ++t) {
        const int n = t2 + 256 * t;
        ua[t] = u0[n]; ub[t] = u1[n];
    }

    inv_s2(data[half], t2, tw2lds);
    __syncthreads();                      // 4: cross-group inv2 -> inv3

    bf16* g0 = gated_t + ((size_t)(b * D1 + ch)) * N_SEQ;
    bf16* g1 = g0 + N_SEQ;
    inv_s3_gate(data[half], t2, tw, ua, ub, g0, g1);
}

// ---------------------------------------------------------------------------
__global__ __launch_bounds__(256) void transpose_cs_kernel(
    const bf16* __restrict__ in, bf16* __restrict__ outp)
{
    __shared__ bf16 tile[64 * 68];
    const int c0 = blockIdx.x * 64;
    const int m0 = blockIdx.y * 64;
    const int b  = m0 >> 11;
    const int s0 = m0 & 2047;
    const int tid = threadIdx.x;
    const int cl = tid >> 4;
    const int sc = (tid & 15) * 4;
    #pragma unroll
    for (int p = 0; p < 4; ++p) {
        int c = p * 16 + cl;
        bf16x4 v = *(const bf16x4*)&in[((size_t)(b * D1 + c0 + c)) * N_SEQ + s0 + sc];
        *(bf16x4*)&tile[c * 68 + sc] = v;
    }
    __syncthreads();
    const int sl = tid >> 4;
    const int cc = (tid & 15) * 4;
    #pragma unroll
    for (int p = 0; p < 4; ++p) {
        int s = p * 16 + sl;
        bf16x4 o;
        #pragma unroll
        for (int j = 0; j < 4; ++j) o[j] = tile[(cc + j) * 68 + s];
        *(bf16x4*)&outp[((size_t)(m0 + s)) * D1 + c0 + cc] = o;
    }
}

// ---------------------------------------------------------------------------
extern "C" void kernel_launch(void* const* d_in, const int* in_sizes, int n_in,
                              void* d_out, int out_size, void* d_ws, size_t ws_size,
                              hipStream_t stream)
{
    const float* x  = (const float*)d_in[0];
    const float* Wu = (const float*)d_in[1];
    const float* bu = (const float*)d_in[2];
    const float* Wv = (const float*)d_in[3];
    const float* bv = (const float*)d_in[4];
    const float* Wo = (const float*)d_in[5];
    const float* bo = (const float*)d_in[6];
    const float* Wp = (const float*)d_in[7];
    const float* bp = (const float*)d_in[8];
    const float* Wl = (const float*)d_in[9];
    const float* bl = (const float*)d_in[10];
    const float* Wr = (const float*)d_in[11];
    const float* br = (const float*)d_in[12];
    float* out = (float*)d_out;

    float* ws      = (float*)d_ws;
    float* a_t     = ws;                       // 1536*4096 fp32; A1spec after fft_a
    float* A0spec  = a_t   + 6291456;          // 768 x 4096 cx
    float* sumsq   = A0spec + 6291456;         // 3 x 4096 fp32
    float* twd     = sumsq + 12288;            // 256 x 16 cx twiddle table
    bf16*  bfws    = (bf16*)(twd + 8192);
    bf16*  x_bf    = bfws;                     // 8192*512
    bf16*  w_bf    = x_bf    + 4194304;        // 5 x 786432: Wu,Wv,Wo,Wl,Wr
    bf16*  Wuv_bf  = w_bf;                     // stacked [Wu;Wv] 3072 x 512
    bf16*  Wo_bf   = w_bf    + 2 * 786432;
    bf16*  Wl_bf   = Wo_bf   + 786432;
    bf16*  Wr_bf   = Wl_bf   + 786432;
    bf16*  gA      = Wr_bf   + 786432;         // 4096*512
    bf16*  gB      = gA      + 2097152;        // 4096*512
    bf16*  u_t     = gB      + 2097152;        // 8192*1536 [b][c][s]
    bf16*  v_t     = u_t     + 12582912;       // 8192*1536 [b][c][s]
    bf16*  gated_t = v_t     + 12582912;       // 8192*1536 [b][c][s]
    bf16*  gated   = gated_t + 12582912;       // 8192*1536 [m][c]

    dim3 blk(256);

    // x/w converts + sumsq zero + rpe input layer + twiddle table
    f2b_all_kernel<<<4096 + 5 * 768 + 12 + 4096 + 16, blk, 0, stream>>>(
        x, Wu, Wv, Wo, Wl, Wr, Wp, bp, x_bf, w_bf, sumsq, gA, twd);

    gemm_bf16<MODE_SILU_UV, 128, bf16><<<dim3(24, 64), blk, 0, stream>>>(
        x_bf, Wuv_bf, bu, bv, u_t, v_t, 8192, 2 * D1, ED, nullptr, nullptr);

    // RPE MLP: srms folded into GEMM epilogues via row-scale commutation.
    bf16* gin = gA;
    bf16* gout = gB;
    for (int i = 0; i < 3; ++i) {
        const float* sin_p = (i == 0) ? nullptr : sumsq + (size_t)(i - 1) * 4096;
        gemm_bf16<MODE_RPE, 64, bf16><<<dim3(8, 32), blk, 0, stream>>>(
            gin, Wl_bf + (size_t)i * ED * ED, bl + (size_t)i * ED, nullptr,
            gout, nullptr, 4096, ED, ED, sin_p, sumsq + (size_t)i * 4096);
        bf16* t = gin; gin = gout; gout = t;
    }
    gemm_bf16<MODE_AT, 64, float><<<dim3(24, 32), blk, 0, stream>>>(
        gin, Wr_bf, br, nullptr, a_t, nullptr, 4096, D1, ED,
        sumsq + 2 * 4096, nullptr);

    fft_a_kernel<<<768, blk, 0, stream>>>(
        a_t, (cx*)A0spec, (cx*)a_t, (const cx*)twd);
    fft_conv_kernel<<<1536, dim3(512), 0, stream>>>(
        v_t, (const cx*)A0spec, (const cx*)a_t, u_t, gated_t, (const cx*)twd);

    transpose_cs_kernel<<<dim3(24, 128), blk, 0, stream>>>(gated_t, gated);

    gemm_bf16<MODE_PLAIN, 64, float><<<dim3(8, 64), blk, 0, stream>>>(
        gated, Wo_bf, bo, nullptr, out, nullptr, 8192, ED, D1,
        nullptr, nullptr);
}